// Round 3
// baseline (875.024 us; speedup 1.0000x reference)
//
#include <hip/hip_runtime.h>
#include <hip/hip_cooperative_groups.h>
#include <math.h>

namespace cg = cooperative_groups;

#define N_ATOM 2048
#define NTOK   512
#define CC     128
#define CZDIM  16
#define HH     4
#define CHD    32
#define NHID   256
#define R1     8      // rows per update work-unit
#define PBSTRIDE 1048576  // 64*4*32*128 floats per block's pair bias

__device__ __forceinline__ float sigm(float x) { return 1.0f / (1.0f + __expf(-x)); }

struct KArgs {
    const float *ql, *cl, *plm, *a2t, *tm;
    const float *gs1, *ws1, *bs1, *wsb1;
    const float *wq, *bq, *wk, *wv;
    const float *gz, *bz, *wz, *wg, *wo, *wog1, *bog1;
    const float *gs2, *ws2, *bs2, *wsb2;
    const float *wt1, *wt2, *wt3, *wog2, *bog2;
    float *q_, *k_, *v_, *g_, *og1_, *tr_, *o_, *pb3, *am, *out;
};

// LDS layouts (union'd in one 58 KB block)
struct SmemU {
    float lna[R1][CC];   // raw a on entry; LN(a) after LN phase
    float sn1[R1][CC];   // LN(cl)*gs1
    float sn2[R1][CC];   // LN(cl)*gs2
    float cls[R1][CC];   // raw cl
    float aln1[R1][CC];  // AdaLN1 output (also g*o scratch)
    float a2s[R1][CC];   // AdaLN2 output
    float hid[R1][NHID]; // SwiGLU hidden
};
struct SmemA {
    float qs[32][36];
    float ks[128][36];
    float vs[128][36];
    float ps[32][132];
};
#define SMEM_FLOATS (sizeof(SmemA) / 4)  // 14592 > sizeof(SmemU)/4 = 8192

// ---------------------------------------------------------------------------
// AdaLN (both) + all row matvecs for one 8-row group. 512 threads.
__device__ void adaln_proj_body(
    SmemU& sm, int t, int n0,
    const float* __restrict__ gs1, const float* __restrict__ ws1,
    const float* __restrict__ bs1, const float* __restrict__ wsb1,
    const float* __restrict__ wq, const float* __restrict__ bq,
    const float* __restrict__ wk, const float* __restrict__ wv,
    const float* __restrict__ wg,
    const float* __restrict__ wog1, const float* __restrict__ bog1,
    const float* __restrict__ gs2, const float* __restrict__ ws2,
    const float* __restrict__ bs2, const float* __restrict__ wsb2,
    const float* __restrict__ wt1, const float* __restrict__ wt2,
    const float* __restrict__ wt3,
    const float* __restrict__ wog2, const float* __restrict__ bog2,
    float* __restrict__ q_o, float* __restrict__ k_o, float* __restrict__ v_o,
    float* __restrict__ g_o, float* __restrict__ og1_o, float* __restrict__ trans_o) {
    // --- LN phase: one wave per row, 64 lanes x 2 elements ---
    {
        int r = t >> 6, l = t & 63;
        float s = 0, s2 = 0;
        for (int k = 0; k < 2; k++) { float x = sm.lna[r][l + 64 * k]; s += x; s2 += x * x; }
        for (int m = 1; m < 64; m <<= 1) { s += __shfl_xor(s, m); s2 += __shfl_xor(s2, m); }
        float mean = s * (1.0f / 128.0f);
        float rs = rsqrtf(s2 * (1.0f / 128.0f) - mean * mean + 1e-5f);
        float cs = 0, cs2 = 0;
        for (int k = 0; k < 2; k++) { float x = sm.cls[r][l + 64 * k]; cs += x; cs2 += x * x; }
        for (int m = 1; m < 64; m <<= 1) { cs += __shfl_xor(cs, m); cs2 += __shfl_xor(cs2, m); }
        float cmean = cs * (1.0f / 128.0f);
        float crs = rsqrtf(cs2 * (1.0f / 128.0f) - cmean * cmean + 1e-5f);
        for (int k = 0; k < 2; k++) {
            int c = l + 64 * k;
            sm.lna[r][c] = (sm.lna[r][c] - mean) * rs;
            float cn = (sm.cls[r][c] - cmean) * crs;
            sm.sn1[r][c] = cn * gs1[c];
            sm.sn2[r][c] = cn * gs2[c];
        }
    }
    __syncthreads();

    const int o = t & 127;
    const int rb = (t >> 7) * 2;  // 2 rows per thread
    float G[2];                   // og2 gate stays in registers

    { // merged: AdaLN1 + AdaLN2 + og1 + og2 gate (6 weight streams)
        float A1[2] = {0, 0}, B1[2] = {0, 0};
        float A2[2] = {0, 0}, B2[2] = {0, 0};
        float O1[2] = {0, 0}, O2[2] = {0, 0};
        for (int c = 0; c < CC; c++) {
            float w_a1 = ws1[c * CC + o], w_b1 = wsb1[c * CC + o];
            float w_a2 = ws2[c * CC + o], w_b2 = wsb2[c * CC + o];
            float w_o1 = wog1[c * CC + o], w_o2 = wog2[c * CC + o];
#pragma unroll
            for (int r = 0; r < 2; r++) {
                float x1 = sm.sn1[rb + r][c], x2 = sm.sn2[rb + r][c], xc = sm.cls[rb + r][c];
                A1[r] += x1 * w_a1; B1[r] += x1 * w_b1;
                A2[r] += x2 * w_a2; B2[r] += x2 * w_b2;
                O1[r] += xc * w_o1; O2[r] += xc * w_o2;
            }
        }
        float b1 = bs1[o], b2 = bs2[o], bo1 = bog1[o], bo2 = bog2[o];
        for (int r = 0; r < 2; r++) {
            sm.aln1[rb + r][o] = sigm(A1[r] + b1) * sm.lna[rb + r][o] + B1[r];
            sm.a2s[rb + r][o]  = sigm(A2[r] + b2) * sm.lna[rb + r][o] + B2[r];
            og1_o[(n0 + rb + r) * CC + o] = sigm(O1[r] + bo1);
            G[r] = sigm(O2[r] + bo2);
        }
    }
    __syncthreads();

    { // q,k,v,g projections from aln1
        float Aq[2] = {0, 0}, Ak[2] = {0, 0}, Av[2] = {0, 0}, Ag[2] = {0, 0};
        for (int c = 0; c < CC; c++) {
            float wqv = wq[c * CC + o], wkv = wk[c * CC + o], wvv = wv[c * CC + o], wgv = wg[c * CC + o];
#pragma unroll
            for (int r = 0; r < 2; r++) {
                float x = sm.aln1[rb + r][c];
                Aq[r] += x * wqv; Ak[r] += x * wkv; Av[r] += x * wvv; Ag[r] += x * wgv;
            }
        }
        float bqv = bq[o];
        for (int r = 0; r < 2; r++) {
            int n = n0 + rb + r;
            q_o[n * CC + o] = Aq[r] + bqv;
            k_o[n * CC + o] = Ak[r];
            v_o[n * CC + o] = Av[r];
            g_o[n * CC + o] = sigm(Ag[r]);
        }
    }
    { // transition hidden: silu(a2@wt1) * (a2@wt2); col = t&255, 4 rows per thread
        const int ht = t & 255, hb = (t >> 8) * 4;
        float A[4] = {0, 0, 0, 0};
        for (int c = 0; c < CC; c++) {
            float w = wt1[c * NHID + ht];
#pragma unroll
            for (int r = 0; r < 4; r++) A[r] += sm.a2s[hb + r][c] * w;
        }
#pragma unroll
        for (int r = 0; r < 4; r++) { float x = A[r]; sm.hid[hb + r][ht] = x * sigm(x); }
        float B[4] = {0, 0, 0, 0};
        for (int c = 0; c < CC; c++) {
            float w = wt2[c * NHID + ht];
#pragma unroll
            for (int r = 0; r < 4; r++) B[r] += sm.a2s[hb + r][c] * w;
        }
#pragma unroll
        for (int r = 0; r < 4; r++) sm.hid[hb + r][ht] *= B[r];
    }
    __syncthreads();
    { // trans = G * (hid @ wt3)
        float A[2] = {0, 0};
        for (int c = 0; c < NHID; c++) {
            float w = wt3[c * CC + o];
#pragma unroll
            for (int r = 0; r < 2; r++) A[r] += sm.hid[rb + r][c] * w;
        }
        for (int r = 0; r < 2; r++)
            trans_o[(n0 + rb + r) * CC + o] = G[r] * A[r];
    }
}

// ---------------------------------------------------------------------------
__device__ void do_update_first(const KArgs& A, SmemU& sm, int t, int unit) {
    const int n0 = unit * R1;
    if (t < 256)
        ((float4*)sm.lna)[t] = ((const float4*)(A.ql + (size_t)n0 * CC))[t];
    else
        ((float4*)sm.cls)[t - 256] = ((const float4*)(A.cl + (size_t)n0 * CC))[t - 256];
    __syncthreads();
    adaln_proj_body(sm, t, n0,
                    A.gs1, A.ws1, A.bs1, A.wsb1, A.wq, A.bq, A.wk, A.wv, A.wg,
                    A.wog1, A.bog1, A.gs2, A.ws2, A.bs2, A.wsb2,
                    A.wt1, A.wt2, A.wt3, A.wog2, A.bog2,
                    A.q_, A.k_, A.v_, A.g_, A.og1_, A.tr_);
}

__device__ void do_update(const KArgs& A, SmemU& sm, int t, int unit, int b) {
    const int n0 = unit * R1;
    const float* wo_prev = A.wo + (size_t)(b - 1) * CC * CC;
    // phase A: gos = g*o into aln1 scratch; cl rows
    if (t < 256) {
        float4 gv = ((const float4*)(A.g_ + (size_t)n0 * CC))[t];
        float4 ov = ((const float4*)(A.o_ + (size_t)n0 * CC))[t];
        float4 p; p.x = gv.x * ov.x; p.y = gv.y * ov.y; p.z = gv.z * ov.z; p.w = gv.w * ov.w;
        ((float4*)sm.aln1)[t] = p;
    } else {
        ((float4*)sm.cls)[t - 256] = ((const float4*)(A.cl + (size_t)n0 * CC))[t - 256];
    }
    __syncthreads();
    {
        const int o = t & 127;
        const int rb = (t >> 7) * 2;
        float Ac[2] = {0, 0};
        for (int c = 0; c < CC; c++) {
            float w = wo_prev[c * CC + o];
#pragma unroll
            for (int r = 0; r < 2; r++) Ac[r] += sm.aln1[rb + r][c] * w;
        }
        for (int r = 0; r < 2; r++) {
            int n = n0 + rb + r;
            sm.lna[rb + r][o] = A.og1_[n * CC + o] * Ac[r] + A.tr_[n * CC + o];
        }
    }
    __syncthreads();
    size_t cc2 = (size_t)b * CC * CC;
    adaln_proj_body(sm, t, n0,
                    A.gs1 + b * CC, A.ws1 + cc2, A.bs1 + b * CC, A.wsb1 + cc2,
                    A.wq + cc2, A.bq + b * CC, A.wk + cc2, A.wv + cc2, A.wg + cc2,
                    A.wog1 + cc2, A.bog1 + b * CC,
                    A.gs2 + b * CC, A.ws2 + cc2, A.bs2 + b * CC, A.wsb2 + cc2,
                    A.wt1 + (size_t)b * CC * NHID, A.wt2 + (size_t)b * CC * NHID,
                    A.wt3 + (size_t)b * NHID * CC,
                    A.wog2 + cc2, A.bog2 + b * CC,
                    A.q_, A.k_, A.v_, A.g_, A.og1_, A.tr_);
}

// ---------------------------------------------------------------------------
// pair-bias unit u in [0,512): 512 threads cover (qb,qi,kj); all 3 NB blocks.
__device__ void do_pb(const KArgs& A, int t, int u) {
    int pid = u * 512 + t;
    int qb = pid >> 12;
    int qi = (pid >> 7) & 31;
    int kj = pid & 127;
    int n = qb * 32 + qi;
    int kstart = max(0, qb * 32 - 48);
    int m = kstart + kj;
    bool valid = (m < N_ATOM);
    float xn[CZDIM];
    if (valid) {
        const float4* p4 = (const float4*)(A.plm + ((size_t)n * N_ATOM + m) * CZDIM);
        float x[CZDIM];
#pragma unroll
        for (int i = 0; i < 4; i++) {
            float4 v = p4[i];
            x[4 * i] = v.x; x[4 * i + 1] = v.y; x[4 * i + 2] = v.z; x[4 * i + 3] = v.w;
        }
        float s = 0, s2 = 0;
#pragma unroll
        for (int c = 0; c < CZDIM; c++) { s += x[c]; s2 += x[c] * x[c]; }
        float mean = s * (1.0f / 16.0f);
        float rs = rsqrtf(s2 * (1.0f / 16.0f) - mean * mean + 1e-5f);
#pragma unroll
        for (int c = 0; c < CZDIM; c++) xn[c] = (x[c] - mean) * rs;
    }
#pragma unroll
    for (int b = 0; b < 3; b++) {
        float out[HH] = {0, 0, 0, 0};
        if (valid) {
            const float* gzb = A.gz + b * CZDIM;
            const float* bzb = A.bz + b * CZDIM;
            const float* wzb = A.wz + b * CZDIM * HH;
#pragma unroll
            for (int c = 0; c < CZDIM; c++) {
                float z = xn[c] * gzb[c] + bzb[c];
#pragma unroll
                for (int h = 0; h < HH; h++) out[h] += z * wzb[c * HH + h];
            }
        }
#pragma unroll
        for (int h = 0; h < HH; h++)
            A.pb3[b * PBSTRIDE + (((qb * HH + h) * 32 + qi) << 7) + kj] = out[h];
    }
}

// amask unit u in [0,256): 8 waves, one row each.
__device__ void do_amask(const KArgs& A, int t, int u) {
    int wave = t >> 6, lane = t & 63;
    int l = u * 8 + wave;
    float s = 0.0f;
    for (int i = lane; i < NTOK; i += 64) s += A.a2t[(size_t)l * NTOK + i] * A.tm[i];
    for (int m = 1; m < 64; m <<= 1) s += __shfl_xor(s, m);
    if (lane == 0) A.am[l] = (s - 1.0f) * 1e9f;
}

// ---------------------------------------------------------------------------
// attention for (qb,h) = unit. 512 threads, 16 per query row.
__device__ void do_attn(const KArgs& A, SmemA& sa, int t, int unit, int b) {
    const float* pb = A.pb3 + (size_t)b * PBSTRIDE;
    const int qb = unit >> 2, h = unit & 3;
    const int n0 = qb * 32;
    const int kstart = max(0, qb * 32 - 48);
    const int nk = min(N_ATOM, qb * 32 + 80) - kstart;

    if (t < 256) {
        int qi = t >> 3, dq = t & 7;
        *(float4*)&sa.qs[qi][dq * 4] = *(const float4*)&A.q_[(n0 + qi) * CC + h * CHD + dq * 4];
    }
    for (int idx = t; idx < 1024; idx += 512) {
        int kj = idx >> 3, dq = idx & 7;
        int m = kstart + kj;
        float4 kv = {0, 0, 0, 0}, vv = {0, 0, 0, 0};
        if (m < N_ATOM) {
            kv = *(const float4*)&A.k_[m * CC + h * CHD + dq * 4];
            vv = *(const float4*)&A.v_[m * CC + h * CHD + dq * 4];
        }
        *(float4*)&sa.ks[kj][dq * 4] = kv;
        *(float4*)&sa.vs[kj][dq * 4] = vv;
    }
    __syncthreads();

    const int qi = t >> 4, j16 = t & 15;
    float4 qr[8];
#pragma unroll
    for (int dq = 0; dq < 8; dq++) qr[dq] = *(const float4*)&sa.qs[qi][dq * 4];

    const float isc = 0.17677669529663687f;  // 1/sqrt(32)
    const float* pbrow = pb + ((qb * HH + h) * 32 + qi) * 128;
    float lr[8];
    float mx = -1e30f;
#pragma unroll
    for (int jj = 0; jj < 8; jj++) {
        int kj = j16 + 16 * jj;
        float acc = 0;
#pragma unroll
        for (int dq = 0; dq < 8; dq++) {
            float4 kk = *(const float4*)&sa.ks[kj][dq * 4];
            acc += qr[dq].x * kk.x + qr[dq].y * kk.y + qr[dq].z * kk.z + qr[dq].w * kk.w;
        }
        float l = (kj < nk) ? (acc * isc + pbrow[kj] + A.am[kstart + kj]) : -1e9f;
        lr[jj] = l;
        mx = fmaxf(mx, l);
    }
    for (int m = 1; m < 16; m <<= 1) mx = fmaxf(mx, __shfl_xor(mx, m));
    float sum = 0;
#pragma unroll
    for (int jj = 0; jj < 8; jj++) { lr[jj] = __expf(lr[jj] - mx); sum += lr[jj]; }
    for (int m = 1; m < 16; m <<= 1) sum += __shfl_xor(sum, m);
    float rd = 1.0f / sum;
#pragma unroll
    for (int jj = 0; jj < 8; jj++) sa.ps[qi][j16 + 16 * jj] = lr[jj] * rd;
    __syncthreads();

    const int d0 = (t & 15) * 2;
    float2 acc = {0, 0};
    for (int kj = 0; kj < 128; kj += 4) {
        float4 pv = *(const float4*)&sa.ps[qi][kj];
        float2 v0 = *(const float2*)&sa.vs[kj][d0];
        float2 v1 = *(const float2*)&sa.vs[kj + 1][d0];
        float2 v2 = *(const float2*)&sa.vs[kj + 2][d0];
        float2 v3 = *(const float2*)&sa.vs[kj + 3][d0];
        acc.x += pv.x * v0.x + pv.y * v1.x + pv.z * v2.x + pv.w * v3.x;
        acc.y += pv.x * v0.y + pv.y * v1.y + pv.z * v2.y + pv.w * v3.y;
    }
    *(float2*)&A.o_[(n0 + qi) * CC + h * CHD + d0] = acc;
}

// ---------------------------------------------------------------------------
// final combine: a_new = og1 * ((g*o) @ wo2) + trans  -> out
__device__ void do_combine(const KArgs& A, SmemU& sm, int t, int unit) {
    const int n0 = unit * R1;
    const float* wo2 = A.wo + (size_t)2 * CC * CC;
    if (t < 256) {
        float4 gv = ((const float4*)(A.g_ + (size_t)n0 * CC))[t];
        float4 ov = ((const float4*)(A.o_ + (size_t)n0 * CC))[t];
        float4 p; p.x = gv.x * ov.x; p.y = gv.y * ov.y; p.z = gv.z * ov.z; p.w = gv.w * ov.w;
        ((float4*)sm.aln1)[t] = p;
    }
    __syncthreads();
    const int o = t & 127, rb = (t >> 7) * 2;
    float Ac[2] = {0, 0};
    for (int c = 0; c < CC; c++) {
        float w = wo2[c * CC + o];
#pragma unroll
        for (int r = 0; r < 2; r++) Ac[r] += sm.aln1[rb + r][c] * w;
    }
    for (int r = 0; r < 2; r++) {
        int n = n0 + rb + r;
        A.out[n * CC + o] = A.og1_[n * CC + o] * Ac[r] + A.tr_[n * CC + o];
    }
}

// ---------------------------------------------------------------------------
// The whole forward pass in ONE cooperative kernel. grid=256, block=512.
// Phase 1: update_first | pair-bias | amask   (1024 units over 256 wg)
// Then per block b: sync; attn(b); sync; [update(b+1) | final combine]
__global__ __launch_bounds__(512) void k_fused(KArgs A) {
    cg::grid_group grid = cg::this_grid();
    __shared__ __align__(16) float smem[SMEM_FLOATS];
    SmemU& sm = *reinterpret_cast<SmemU*>(smem);
    SmemA& sa = *reinterpret_cast<SmemA*>(smem);
    const int wg = blockIdx.x;
    const int t = threadIdx.x;

    for (int u = wg; u < 1024; u += 256) {
        if (u < 256) do_update_first(A, sm, t, u);
        else if (u < 768) do_pb(A, t, u - 256);
        else do_amask(A, t, u - 768);
    }
    for (int b = 0; b < 3; b++) {
        grid.sync();
        do_attn(A, sa, t, wg, b);
        grid.sync();
        if (b < 2) do_update(A, sm, t, wg, b + 1);
        else do_combine(A, sm, t, wg);
    }
}

// ---------------------------------------------------------------------------
extern "C" void kernel_launch(void* const* d_in, const int* in_sizes, int n_in,
                              void* d_out, int out_size, void* d_ws, size_t ws_size,
                              hipStream_t stream) {
    const size_t NC = (size_t)N_ATOM * CC;  // 262144
    float* ws = (float*)d_ws;

    KArgs ka;
    ka.ql   = (const float*)d_in[0];
    ka.cl   = (const float*)d_in[1];
    ka.plm  = (const float*)d_in[2];
    ka.a2t  = (const float*)d_in[3];
    ka.tm   = (const float*)d_in[4];
    ka.gs1  = (const float*)d_in[5];
    ka.ws1  = (const float*)d_in[6];
    ka.bs1  = (const float*)d_in[7];
    ka.wsb1 = (const float*)d_in[8];
    ka.wq   = (const float*)d_in[9];
    ka.bq   = (const float*)d_in[10];
    ka.wk   = (const float*)d_in[11];
    ka.wv   = (const float*)d_in[12];
    ka.gz   = (const float*)d_in[13];
    ka.bz   = (const float*)d_in[14];
    ka.wz   = (const float*)d_in[15];
    ka.wg   = (const float*)d_in[16];
    ka.wo   = (const float*)d_in[17];
    ka.wog1 = (const float*)d_in[18];
    ka.bog1 = (const float*)d_in[19];
    ka.gs2  = (const float*)d_in[20];
    ka.ws2  = (const float*)d_in[21];
    ka.bs2  = (const float*)d_in[22];
    ka.wsb2 = (const float*)d_in[23];
    ka.wt1  = (const float*)d_in[24];
    ka.wt2  = (const float*)d_in[25];
    ka.wt3  = (const float*)d_in[26];
    ka.wog2 = (const float*)d_in[27];
    ka.bog2 = (const float*)d_in[28];

    ka.q_   = ws + 0 * NC;
    ka.k_   = ws + 1 * NC;
    ka.v_   = ws + 2 * NC;
    ka.g_   = ws + 3 * NC;
    ka.og1_ = ws + 4 * NC;
    ka.tr_  = ws + 5 * NC;
    ka.o_   = ws + 6 * NC;
    ka.pb3  = ws + 7 * NC;                    // 3 * 1048576 floats
    ka.am   = ws + 7 * NC + 3 * PBSTRIDE;     // 2048 floats
    ka.out  = (float*)d_out;

    void* args[] = {&ka};
    hipLaunchCooperativeKernel((const void*)k_fused, dim3(256), dim3(512),
                               args, 0, stream);
}

// Round 4
// 530.347 us; speedup vs baseline: 1.6499x; 1.6499x over previous
//
#include <hip/hip_runtime.h>
#include <math.h>

#define N_ATOM 2048
#define NTOK   512
#define CC     128
#define CZDIM  16
#define HH     4
#define CHD    32
#define NHID   256
#define NQB    64     // 2048 / 32 query blocks
#define R1     8      // rows per update workgroup
#define PBSTRIDE 1048576  // 64*4*32*128 floats per block's pair bias

__device__ __forceinline__ float sigm(float x) { return 1.0f / (1.0f + __expf(-x)); }

// ---------------------------------------------------------------------------
// LDS layout for the update kernels (64 KB).
struct SmemU {
    float lna[R1][CC];      // raw a on entry; LN(a) after LN phase
    float sn1[R1][CC];      // LN(cl)*gs1
    float sn2[R1][CC];      // LN(cl)*gs2
    float cls[R1][CC];      // raw cl
    float aln1[R1][CC];     // AdaLN1 output (also g*o scratch in phase W)
    float a2s[R1][CC];      // AdaLN2 output
    float hid[R1][NHID];    // SwiGLU hidden
    float tmpA[4][R1][CC];  // partial/stream results
    float tmpB[4][R1][CC];  // partial/stream results (wog1/wog2)
};

// ---------------------------------------------------------------------------
// Core matvec tile: 4 LDS rows (stride LDX) x 2 output cols, c-range [c0,c0+nc).
// x reads are wave-uniform ds_read_b128; weights are float2 global loads
// (each weight word read ONCE per workgroup across the whole phase).
template<int LDX>
__device__ __forceinline__ void mv_acc(const float* Xbase, int c0, int nc,
                                       const float* __restrict__ W, int ldw,
                                       int col2, float2 acc[4]) {
    for (int c = c0; c < c0 + nc; c += 4) {
        float2 w0 = *(const float2*)(W + (size_t)(c + 0) * ldw + col2);
        float2 w1 = *(const float2*)(W + (size_t)(c + 1) * ldw + col2);
        float2 w2 = *(const float2*)(W + (size_t)(c + 2) * ldw + col2);
        float2 w3 = *(const float2*)(W + (size_t)(c + 3) * ldw + col2);
#pragma unroll
        for (int r = 0; r < 4; r++) {
            float4 xv = *(const float4*)(Xbase + r * LDX + c);
            acc[r].x += xv.x * w0.x + xv.y * w1.x + xv.z * w2.x + xv.w * w3.x;
            acc[r].y += xv.x * w0.y + xv.y * w1.y + xv.z * w2.y + xv.w * w3.y;
        }
    }
}

// ---------------------------------------------------------------------------
// AdaLN (both) + all projections for one 8-row group. 512 threads.
// Streams are split across waves so each weight matrix is read once per wg.
__device__ void adaln_proj_body(
    SmemU& sm, int t, int n0,
    const float* __restrict__ gs1, const float* __restrict__ ws1,
    const float* __restrict__ bs1, const float* __restrict__ wsb1,
    const float* __restrict__ wq, const float* __restrict__ bq,
    const float* __restrict__ wk, const float* __restrict__ wv,
    const float* __restrict__ wg,
    const float* __restrict__ wog1, const float* __restrict__ bog1,
    const float* __restrict__ gs2, const float* __restrict__ ws2,
    const float* __restrict__ bs2, const float* __restrict__ wsb2,
    const float* __restrict__ wt1, const float* __restrict__ wt2,
    const float* __restrict__ wt3,
    const float* __restrict__ wog2, const float* __restrict__ bog2,
    float* __restrict__ q_o, float* __restrict__ k_o, float* __restrict__ v_o,
    float* __restrict__ g_o, float* __restrict__ og1_o, float* __restrict__ trans_o) {
    // --- LN phase: one wave per row, 64 lanes x 2 elements ---
    {
        int r = t >> 6, l = t & 63;
        float s = 0, s2 = 0;
#pragma unroll
        for (int k = 0; k < 2; k++) { float x = sm.lna[r][l + 64 * k]; s += x; s2 += x * x; }
        for (int m = 1; m < 64; m <<= 1) { s += __shfl_xor(s, m); s2 += __shfl_xor(s2, m); }
        float mean = s * (1.0f / 128.0f);
        float rs = rsqrtf(s2 * (1.0f / 128.0f) - mean * mean + 1e-5f);
        float cs = 0, cs2 = 0;
#pragma unroll
        for (int k = 0; k < 2; k++) { float x = sm.cls[r][l + 64 * k]; cs += x; cs2 += x * x; }
        for (int m = 1; m < 64; m <<= 1) { cs += __shfl_xor(cs, m); cs2 += __shfl_xor(cs2, m); }
        float cmean = cs * (1.0f / 128.0f);
        float crs = rsqrtf(cs2 * (1.0f / 128.0f) - cmean * cmean + 1e-5f);
#pragma unroll
        for (int k = 0; k < 2; k++) {
            int c = l + 64 * k;
            sm.lna[r][c] = (sm.lna[r][c] - mean) * rs;
            float cn = (sm.cls[r][c] - cmean) * crs;
            sm.sn1[r][c] = cn * gs1[c];
            sm.sn2[r][c] = cn * gs2[c];
        }
    }
    __syncthreads();

    // --- M1: streams {ws1,wsb1,ws2,wsb2} one per wave-pair; M2: wog1/wog2 c-split ---
    {
        int rh = (t >> 6) & 1, l = t & 63, col2 = 2 * l;
        {
            int s = t >> 7;
            const float* X = (s < 2) ? &sm.sn1[rh * 4][0] : &sm.sn2[rh * 4][0];
            const float* W = (s == 0) ? ws1 : (s == 1) ? wsb1 : (s == 2) ? ws2 : wsb2;
            float2 acc[4] = {{0,0},{0,0},{0,0},{0,0}};
            mv_acc<CC>(X, 0, CC, W, CC, col2, acc);
#pragma unroll
            for (int r = 0; r < 4; r++)
                *(float2*)&sm.tmpA[s][rh * 4 + r][col2] = acc[r];
        }
        {
            int s2 = t >> 8, ch = (t >> 7) & 1;
            const float* W = s2 ? wog2 : wog1;
            float2 acc[4] = {{0,0},{0,0},{0,0},{0,0}};
            mv_acc<CC>(&sm.cls[rh * 4][0], ch * 64, 64, W, CC, col2, acc);
#pragma unroll
            for (int r = 0; r < 4; r++)
                *(float2*)&sm.tmpB[s2 * 2 + ch][rh * 4 + r][col2] = acc[r];
        }
    }
    __syncthreads();

    float G[2];  // og2 gate, stays in registers until T3 epilogue (same thread map)
    {
        int o = t & 127, g = t >> 7;
#pragma unroll
        for (int r = 0; r < 2; r++) {
            int rr = 2 * g + r;
            float A1 = sm.tmpA[0][rr][o], B1 = sm.tmpA[1][rr][o];
            float A2 = sm.tmpA[2][rr][o], B2 = sm.tmpA[3][rr][o];
            float O1 = sm.tmpB[0][rr][o] + sm.tmpB[1][rr][o];
            float O2 = sm.tmpB[2][rr][o] + sm.tmpB[3][rr][o];
            float ln = sm.lna[rr][o];
            sm.aln1[rr][o] = sigm(A1 + bs1[o]) * ln + B1;
            sm.a2s [rr][o] = sigm(A2 + bs2[o]) * ln + B2;
            og1_o[(size_t)(n0 + rr) * CC + o] = sigm(O1 + bog1[o]);
            G[r] = sigm(O2 + bog2[o]);
        }
    }
    __syncthreads();

    // --- Q: streams {wq,wk,wv,wg} one per wave-pair; direct global stores ---
    {
        int s = t >> 7, rh = (t >> 6) & 1, l = t & 63, col2 = 2 * l;
        const float* W = (s == 0) ? wq : (s == 1) ? wk : (s == 2) ? wv : wg;
        float2 acc[4] = {{0,0},{0,0},{0,0},{0,0}};
        mv_acc<CC>(&sm.aln1[rh * 4][0], 0, CC, W, CC, col2, acc);
        float* dst = (s == 0) ? q_o : (s == 1) ? k_o : (s == 2) ? v_o : g_o;
#pragma unroll
        for (int r = 0; r < 4; r++) {
            float2 v = acc[r];
            if (s == 0) { v.x += bq[col2]; v.y += bq[col2 + 1]; }
            if (s == 3) { v.x = sigm(v.x); v.y = sigm(v.y); }
            *(float2*)&dst[(size_t)(n0 + rh * 4 + r) * CC + col2] = v;
        }
    }

    // --- T12: wt1 (silu) / wt2 split by stream; 2 cols x 4 rows per thread ---
    int sT, rhT, colT;
    float2 accT[4] = {{0,0},{0,0},{0,0},{0,0}};
    {
        sT = t >> 8; rhT = (t >> 7) & 1; colT = 2 * (t & 127);
        const float* W = sT ? wt2 : wt1;
        mv_acc<CC>(&sm.a2s[rhT * 4][0], 0, CC, W, NHID, colT, accT);
        if (sT == 0) {
#pragma unroll
            for (int r = 0; r < 4; r++) {
                float2 h;
                h.x = accT[r].x * sigm(accT[r].x);
                h.y = accT[r].y * sigm(accT[r].y);
                *(float2*)&sm.hid[rhT * 4 + r][colT] = h;
            }
        }
    }
    __syncthreads();
    if (sT == 1) {
#pragma unroll
        for (int r = 0; r < 4; r++) {
            float2 h = *(float2*)&sm.hid[rhT * 4 + r][colT];
            h.x *= accT[r].x; h.y *= accT[r].y;
            *(float2*)&sm.hid[rhT * 4 + r][colT] = h;
        }
    }
    __syncthreads();

    // --- T3: wt3 (256->128), 4-way c-split + LDS reduce; gate with G ---
    {
        int cq = t >> 7, rh = (t >> 6) & 1, l = t & 63, col2 = 2 * l;
        float2 acc[4] = {{0,0},{0,0},{0,0},{0,0}};
        mv_acc<NHID>(&sm.hid[rh * 4][0], cq * 64, 64, wt3, CC, col2, acc);
#pragma unroll
        for (int r = 0; r < 4; r++)
            *(float2*)&sm.tmpA[cq][rh * 4 + r][col2] = acc[r];
    }
    __syncthreads();
    {
        int o = t & 127, g = t >> 7;
#pragma unroll
        for (int r = 0; r < 2; r++) {
            int rr = 2 * g + r;
            float s4 = sm.tmpA[0][rr][o] + sm.tmpA[1][rr][o]
                     + sm.tmpA[2][rr][o] + sm.tmpA[3][rr][o];
            trans_o[(size_t)(n0 + rr) * CC + o] = G[r] * s4;
        }
    }
}

// ---------------------------------------------------------------------------
// First block: a = ql straight from global.
__global__ __launch_bounds__(512) void k_update_first(
    const float* __restrict__ a_in, const float* __restrict__ cl,
    const float* __restrict__ gs1, const float* __restrict__ ws1,
    const float* __restrict__ bs1, const float* __restrict__ wsb1,
    const float* __restrict__ wq, const float* __restrict__ bq,
    const float* __restrict__ wk, const float* __restrict__ wv,
    const float* __restrict__ wg,
    const float* __restrict__ wog1, const float* __restrict__ bog1,
    const float* __restrict__ gs2, const float* __restrict__ ws2,
    const float* __restrict__ bs2, const float* __restrict__ wsb2,
    const float* __restrict__ wt1, const float* __restrict__ wt2,
    const float* __restrict__ wt3,
    const float* __restrict__ wog2, const float* __restrict__ bog2,
    float* __restrict__ q_o, float* __restrict__ k_o, float* __restrict__ v_o,
    float* __restrict__ g_o, float* __restrict__ og1_o, float* __restrict__ trans_o) {
    __shared__ SmemU sm;
    const int t = threadIdx.x;
    const int n0 = blockIdx.x * R1;
    ((float2*)sm.lna)[t] = ((const float2*)(a_in + (size_t)n0 * CC))[t];
    ((float2*)sm.cls)[t] = ((const float2*)(cl + (size_t)n0 * CC))[t];
    __syncthreads();
    adaln_proj_body(sm, t, n0, gs1, ws1, bs1, wsb1, wq, bq, wk, wv, wg, wog1, bog1,
                    gs2, ws2, bs2, wsb2, wt1, wt2, wt3, wog2, bog2,
                    q_o, k_o, v_o, g_o, og1_o, trans_o);
}

// ---------------------------------------------------------------------------
// Later blocks: fused combine (a = og1*((g*o)@wo)+trans, 4-way c-split) + body.
__global__ __launch_bounds__(512) void k_update(
    const float* __restrict__ cl,
    const float* __restrict__ g_in, const float* __restrict__ o_in,
    const float* __restrict__ og1_in, const float* __restrict__ trans_in,
    const float* __restrict__ wo_prev,
    const float* __restrict__ gs1, const float* __restrict__ ws1,
    const float* __restrict__ bs1, const float* __restrict__ wsb1,
    const float* __restrict__ wq, const float* __restrict__ bq,
    const float* __restrict__ wk, const float* __restrict__ wv,
    const float* __restrict__ wg,
    const float* __restrict__ wog1, const float* __restrict__ bog1,
    const float* __restrict__ gs2, const float* __restrict__ ws2,
    const float* __restrict__ bs2, const float* __restrict__ wsb2,
    const float* __restrict__ wt1, const float* __restrict__ wt2,
    const float* __restrict__ wt3,
    const float* __restrict__ wog2, const float* __restrict__ bog2,
    float* __restrict__ q_o, float* __restrict__ k_o, float* __restrict__ v_o,
    float* __restrict__ g_o, float* __restrict__ og1_o, float* __restrict__ trans_o) {
    __shared__ SmemU sm;
    const int t = threadIdx.x;
    const int n0 = blockIdx.x * R1;
    {   // stage gos = g*o into aln1 scratch; cl rows
        float2 gv = ((const float2*)(g_in + (size_t)n0 * CC))[t];
        float2 ov = ((const float2*)(o_in + (size_t)n0 * CC))[t];
        float2 p; p.x = gv.x * ov.x; p.y = gv.y * ov.y;
        ((float2*)sm.aln1)[t] = p;
        ((float2*)sm.cls)[t] = ((const float2*)(cl + (size_t)n0 * CC))[t];
    }
    __syncthreads();
    {   // phase W: (g*o) @ wo, 4-way c-split
        int cq = t >> 7, rh = (t >> 6) & 1, l = t & 63, col2 = 2 * l;
        float2 acc[4] = {{0,0},{0,0},{0,0},{0,0}};
        mv_acc<CC>(&sm.aln1[rh * 4][0], cq * 32, 32, wo_prev, CC, col2, acc);
#pragma unroll
        for (int r = 0; r < 4; r++)
            *(float2*)&sm.tmpA[cq][rh * 4 + r][col2] = acc[r];
    }
    __syncthreads();
    {   // reduce + gate + residual -> new a in lna
        int o = t & 127, g = t >> 7;
#pragma unroll
        for (int r = 0; r < 2; r++) {
            int rr = 2 * g + r;
            float s4 = sm.tmpA[0][rr][o] + sm.tmpA[1][rr][o]
                     + sm.tmpA[2][rr][o] + sm.tmpA[3][rr][o];
            sm.lna[rr][o] = og1_in[(size_t)(n0 + rr) * CC + o] * s4
                          + trans_in[(size_t)(n0 + rr) * CC + o];
        }
    }
    __syncthreads();
    adaln_proj_body(sm, t, n0, gs1, ws1, bs1, wsb1, wq, bq, wk, wv, wg, wog1, bog1,
                    gs2, ws2, bs2, wsb2, wt1, wt2, wt3, wog2, bog2,
                    q_o, k_o, v_o, g_o, og1_o, trans_o);
}

// ---------------------------------------------------------------------------
// Final combine only (writes d_out): a_new = og1 * ((g*o) @ wo) + trans
__global__ __launch_bounds__(512) void k_combine(const float* __restrict__ g,
                                                 const float* __restrict__ o_in,
                                                 const float* __restrict__ og1,
                                                 const float* __restrict__ trans,
                                                 const float* __restrict__ wo,
                                                 float* __restrict__ a_out) {
    __shared__ SmemU sm;
    const int t = threadIdx.x;
    const int n0 = blockIdx.x * R1;
    {
        float2 gv = ((const float2*)(g + (size_t)n0 * CC))[t];
        float2 ov = ((const float2*)(o_in + (size_t)n0 * CC))[t];
        float2 p; p.x = gv.x * ov.x; p.y = gv.y * ov.y;
        ((float2*)sm.aln1)[t] = p;
    }
    __syncthreads();
    {
        int cq = t >> 7, rh = (t >> 6) & 1, l = t & 63, col2 = 2 * l;
        float2 acc[4] = {{0,0},{0,0},{0,0},{0,0}};
        mv_acc<CC>(&sm.aln1[rh * 4][0], cq * 32, 32, wo, CC, col2, acc);
#pragma unroll
        for (int r = 0; r < 4; r++)
            *(float2*)&sm.tmpA[cq][rh * 4 + r][col2] = acc[r];
    }
    __syncthreads();
    {
        int o = t & 127, g2 = t >> 7;
#pragma unroll
        for (int r = 0; r < 2; r++) {
            int rr = 2 * g2 + r;
            float s4 = sm.tmpA[0][rr][o] + sm.tmpA[1][rr][o]
                     + sm.tmpA[2][rr][o] + sm.tmpA[3][rr][o];
            a_out[(size_t)(n0 + rr) * CC + o] =
                og1[(size_t)(n0 + rr) * CC + o] * s4
                + trans[(size_t)(n0 + rr) * CC + o];
        }
    }
}

// ---------------------------------------------------------------------------
// K_pb3 + amask fused (unchanged from round 2).
__global__ __launch_bounds__(256) void k_pb3_amask(const float* __restrict__ plm,
                                                   const float* __restrict__ gz,
                                                   const float* __restrict__ bz,
                                                   const float* __restrict__ wz,
                                                   const float* __restrict__ a2t,
                                                   const float* __restrict__ tm,
                                                   float* __restrict__ pb,
                                                   float* __restrict__ amask) {
    if (blockIdx.x >= 1024) {
        int wave = threadIdx.x >> 6, lane = threadIdx.x & 63;
        int l = (blockIdx.x - 1024) * 4 + wave;
        float s = 0.0f;
        for (int i = lane; i < NTOK; i += 64) s += a2t[(size_t)l * NTOK + i] * tm[i];
        for (int m = 1; m < 64; m <<= 1) s += __shfl_xor(s, m);
        if (lane == 0) amask[l] = (s - 1.0f) * 1e9f;
        return;
    }
    int pid = blockIdx.x * 256 + threadIdx.x;
    int qb = pid >> 12;
    int qi = (pid >> 7) & 31;
    int kj = pid & 127;
    int n = qb * 32 + qi;
    int kstart = max(0, qb * 32 - 48);
    int m = kstart + kj;
    bool valid = (m < N_ATOM);
    float xn[CZDIM];
    if (valid) {
        const float4* p4 = (const float4*)(plm + ((size_t)n * N_ATOM + m) * CZDIM);
        float x[CZDIM];
#pragma unroll
        for (int i = 0; i < 4; i++) {
            float4 v = p4[i];
            x[4 * i] = v.x; x[4 * i + 1] = v.y; x[4 * i + 2] = v.z; x[4 * i + 3] = v.w;
        }
        float s = 0, s2 = 0;
#pragma unroll
        for (int c = 0; c < CZDIM; c++) { s += x[c]; s2 += x[c] * x[c]; }
        float mean = s * (1.0f / 16.0f);
        float rs = rsqrtf(s2 * (1.0f / 16.0f) - mean * mean + 1e-5f);
#pragma unroll
        for (int c = 0; c < CZDIM; c++) xn[c] = (x[c] - mean) * rs;
    }
#pragma unroll
    for (int b = 0; b < 3; b++) {
        float out[HH] = {0, 0, 0, 0};
        if (valid) {
            const float* gzb = gz + b * CZDIM;
            const float* bzb = bz + b * CZDIM;
            const float* wzb = wz + b * CZDIM * HH;
#pragma unroll
            for (int c = 0; c < CZDIM; c++) {
                float z = xn[c] * gzb[c] + bzb[c];
#pragma unroll
                for (int h = 0; h < HH; h++) out[h] += z * wzb[c * HH + h];
            }
        }
#pragma unroll
        for (int h = 0; h < HH; h++)
            pb[b * PBSTRIDE + (((qb * HH + h) * 32 + qi) << 7) + kj] = out[h];
    }
}

// ---------------------------------------------------------------------------
// K_attn (unchanged from round 2): one wg per (query block, head), 512 thr.
__global__ __launch_bounds__(512) void k_attn(const float* __restrict__ q,
                                              const float* __restrict__ k,
                                              const float* __restrict__ v,
                                              const float* __restrict__ pb,
                                              const float* __restrict__ amask,
                                              float* __restrict__ o_out) {
    __shared__ __align__(16) float qs[32][36];
    __shared__ __align__(16) float ks[128][36];
    __shared__ __align__(16) float vs[128][36];
    __shared__ __align__(16) float ps[32][132];
    const int t = threadIdx.x;
    const int qb = blockIdx.x >> 2, h = blockIdx.x & 3;
    const int n0 = qb * 32;
    const int kstart = max(0, qb * 32 - 48);
    const int nk = min(N_ATOM, qb * 32 + 80) - kstart;

    if (t < 256) {
        int qi = t >> 3, dq = t & 7;
        *(float4*)&qs[qi][dq * 4] = *(const float4*)&q[(n0 + qi) * CC + h * CHD + dq * 4];
    }
    for (int idx = t; idx < 1024; idx += 512) {
        int kj = idx >> 3, dq = idx & 7;
        int m = kstart + kj;
        float4 kv = {0, 0, 0, 0}, vv = {0, 0, 0, 0};
        if (m < N_ATOM) {
            kv = *(const float4*)&k[m * CC + h * CHD + dq * 4];
            vv = *(const float4*)&v[m * CC + h * CHD + dq * 4];
        }
        *(float4*)&ks[kj][dq * 4] = kv;
        *(float4*)&vs[kj][dq * 4] = vv;
    }
    __syncthreads();

    const int qi = t >> 4, j16 = t & 15;
    float4 qr[8];
#pragma unroll
    for (int dq = 0; dq < 8; dq++) qr[dq] = *(const float4*)&qs[qi][dq * 4];

    const float isc = 0.17677669529663687f;  // 1/sqrt(32)
    const float* pbrow = pb + ((qb * HH + h) * 32 + qi) * 128;
    float lr[8];
    float mx = -1e30f;
#pragma unroll
    for (int jj = 0; jj < 8; jj++) {
        int kj = j16 + 16 * jj;
        float acc = 0;
#pragma unroll
        for (int dq = 0; dq < 8; dq++) {
            float4 kk = *(const float4*)&ks[kj][dq * 4];
            acc += qr[dq].x * kk.x + qr[dq].y * kk.y + qr[dq].z * kk.z + qr[dq].w * kk.w;
        }
        float l = (kj < nk) ? (acc * isc + pbrow[kj] + amask[kstart + kj]) : -1e9f;
        lr[jj] = l;
        mx = fmaxf(mx, l);
    }
    for (int m = 1; m < 16; m <<= 1) mx = fmaxf(mx, __shfl_xor(mx, m));
    float sum = 0;
#pragma unroll
    for (int jj = 0; jj < 8; jj++) { lr[jj] = __expf(lr[jj] - mx); sum += lr[jj]; }
    for (int m = 1; m < 16; m <<= 1) sum += __shfl_xor(sum, m);
    float rd = 1.0f / sum;
#pragma unroll
    for (int jj = 0; jj < 8; jj++) ps[qi][j16 + 16 * jj] = lr[jj] * rd;
    __syncthreads();

    const int d0 = (t & 15) * 2;
    float2 acc = {0, 0};
    for (int kj = 0; kj < 128; kj += 4) {
        float4 pv = *(const float4*)&ps[qi][kj];
        float2 v0 = *(const float2*)&vs[kj][d0];
        float2 v1 = *(const float2*)&vs[kj + 1][d0];
        float2 v2 = *(const float2*)&vs[kj + 2][d0];
        float2 v3 = *(const float2*)&vs[kj + 3][d0];
        acc.x += pv.x * v0.x + pv.y * v1.x + pv.z * v2.x + pv.w * v3.x;
        acc.y += pv.x * v0.y + pv.y * v1.y + pv.z * v2.y + pv.w * v3.y;
    }
    *(float2*)&o_out[(n0 + qi) * CC + h * CHD + d0] = acc;
}

// ---------------------------------------------------------------------------
extern "C" void kernel_launch(void* const* d_in, const int* in_sizes, int n_in,
                              void* d_out, int out_size, void* d_ws, size_t ws_size,
                              hipStream_t stream) {
    const float* ql   = (const float*)d_in[0];
    const float* cl   = (const float*)d_in[1];
    const float* plm  = (const float*)d_in[2];
    const float* a2t  = (const float*)d_in[3];
    const float* tm   = (const float*)d_in[4];
    const float* ada1_gs  = (const float*)d_in[5];
    const float* ada1_ws  = (const float*)d_in[6];
    const float* ada1_bs  = (const float*)d_in[7];
    const float* ada1_wsb = (const float*)d_in[8];
    const float* wq  = (const float*)d_in[9];
    const float* bq  = (const float*)d_in[10];
    const float* wk  = (const float*)d_in[11];
    const float* wv  = (const float*)d_in[12];
    const float* gz  = (const float*)d_in[13];
    const float* bz  = (const float*)d_in[14];
    const float* wz  = (const float*)d_in[15];
    const float* wg  = (const float*)d_in[16];
    const float* wo  = (const float*)d_in[17];
    const float* wog1 = (const float*)d_in[18];
    const float* bog1 = (const float*)d_in[19];
    const float* ada2_gs  = (const float*)d_in[20];
    const float* ada2_ws  = (const float*)d_in[21];
    const float* ada2_bs  = (const float*)d_in[22];
    const float* ada2_wsb = (const float*)d_in[23];
    const float* wt1 = (const float*)d_in[24];
    const float* wt2 = (const float*)d_in[25];
    const float* wt3 = (const float*)d_in[26];
    const float* wog2 = (const float*)d_in[27];
    const float* bog2 = (const float*)d_in[28];

    const size_t NC = (size_t)N_ATOM * CC;  // 262144
    float* ws = (float*)d_ws;
    float* q_    = ws + 0 * NC;
    float* k_    = ws + 1 * NC;
    float* v_    = ws + 2 * NC;
    float* g_    = ws + 3 * NC;
    float* og1_  = ws + 4 * NC;
    float* tr_   = ws + 5 * NC;
    float* o_    = ws + 6 * NC;
    float* pb3   = ws + 7 * NC;                      // 3 * 1048576 floats
    float* am    = ws + 7 * NC + 3 * PBSTRIDE;       // 2048 floats

    k_pb3_amask<<<1536, 256, 0, stream>>>(plm, gz, bz, wz, a2t, tm, pb3, am);

    for (int b = 0; b < 3; b++) {
        if (b == 0) {
            k_update_first<<<N_ATOM / R1, 512, 0, stream>>>(
                ql, cl,
                ada1_gs, ada1_ws, ada1_bs, ada1_wsb,
                wq, bq, wk, wv, wg, wog1, bog1,
                ada2_gs, ada2_ws, ada2_bs, ada2_wsb,
                wt1, wt2, wt3, wog2, bog2,
                q_, k_, v_, g_, og1_, tr_);
        } else {
            k_update<<<N_ATOM / R1, 512, 0, stream>>>(
                cl, g_, o_, og1_, tr_, wo + (size_t)(b - 1) * CC * CC,
                ada1_gs + b * CC, ada1_ws + (size_t)b * CC * CC, ada1_bs + b * CC,
                ada1_wsb + (size_t)b * CC * CC,
                wq + (size_t)b * CC * CC, bq + b * CC, wk + (size_t)b * CC * CC,
                wv + (size_t)b * CC * CC, wg + (size_t)b * CC * CC,
                wog1 + (size_t)b * CC * CC, bog1 + b * CC,
                ada2_gs + b * CC, ada2_ws + (size_t)b * CC * CC, ada2_bs + b * CC,
                ada2_wsb + (size_t)b * CC * CC,
                wt1 + (size_t)b * CC * NHID, wt2 + (size_t)b * CC * NHID,
                wt3 + (size_t)b * NHID * CC,
                wog2 + (size_t)b * CC * CC, bog2 + b * CC,
                q_, k_, v_, g_, og1_, tr_);
        }
        k_attn<<<NQB * HH, 512, 0, stream>>>(q_, k_, v_, pb3 + (size_t)b * PBSTRIDE, am, o_);
    }
    k_combine<<<N_ATOM / R1, 512, 0, stream>>>(g_, o_, og1_, tr_, wo + (size_t)2 * CC * CC,
                                               (float*)d_out);
}

// Round 5
// 525.520 us; speedup vs baseline: 1.6651x; 1.0092x over previous
//
#include <hip/hip_runtime.h>
#include <math.h>

#define N_ATOM 2048
#define NTOK   512
#define CC     128
#define CZDIM  16
#define HH     4
#define CHD    32
#define NHID   256
#define NQB    64     // 2048 / 32 query blocks
#define R1     8      // rows per update workgroup
#define PBSTRIDE 1048576  // 64*4*32*128 floats per block's pair bias

__device__ __forceinline__ float sigm(float x) { return 1.0f / (1.0f + __expf(-x)); }

// ---------------------------------------------------------------------------
// LDS layout for the update kernels (64 KB).
struct SmemU {
    float lna[R1][CC];      // raw a on entry; LN(a) after LN phase
    float sn1[R1][CC];      // LN(cl)*gs1
    float sn2[R1][CC];      // LN(cl)*gs2
    float cls[R1][CC];      // raw cl
    float aln1[R1][CC];     // AdaLN1 output (also g*o scratch in phase W)
    float a2s[R1][CC];      // AdaLN2 output
    float hid[R1][NHID];    // SwiGLU hidden (silu(wt1) then *= wt2)
    float tmp[8][R1][CC];   // stream/partial results (32 KB)
};

// ---------------------------------------------------------------------------
// Core matvec tile: 4 LDS rows (stride LDX) x 2 output cols, c in [c0,c0+nc).
// x reads are wave-uniform ds_read_b128 broadcasts; weights are float2 global
// loads — each weight word is read ONCE per workgroup across a phase.
template<int LDX>
__device__ __forceinline__ void mv_acc(const float* Xbase, int c0, int nc,
                                       const float* __restrict__ W, int ldw,
                                       int col2, float2 acc[4]) {
    for (int c = c0; c < c0 + nc; c += 4) {
        float2 w0 = *(const float2*)(W + (size_t)(c + 0) * ldw + col2);
        float2 w1 = *(const float2*)(W + (size_t)(c + 1) * ldw + col2);
        float2 w2 = *(const float2*)(W + (size_t)(c + 2) * ldw + col2);
        float2 w3 = *(const float2*)(W + (size_t)(c + 3) * ldw + col2);
#pragma unroll
        for (int r = 0; r < 4; r++) {
            float4 xv = *(const float4*)(Xbase + r * LDX + c);
            acc[r].x += xv.x * w0.x + xv.y * w1.x + xv.z * w2.x + xv.w * w3.x;
            acc[r].y += xv.x * w0.y + xv.y * w1.y + xv.z * w2.y + xv.w * w3.y;
        }
    }
}

// ---------------------------------------------------------------------------
// AdaLN (both) + all projections for one 8-row group. 1024 threads:
// phases run wide (M1 || og-gates; QKVG || SwiGLU) for 4 waves/SIMD latency
// hiding at grid=256 (1 wg/CU).
__device__ void adaln_proj_body(
    SmemU& sm, int t, int n0,
    const float* __restrict__ gs1, const float* __restrict__ ws1,
    const float* __restrict__ bs1, const float* __restrict__ wsb1,
    const float* __restrict__ wq, const float* __restrict__ bq,
    const float* __restrict__ wk, const float* __restrict__ wv,
    const float* __restrict__ wg,
    const float* __restrict__ wog1, const float* __restrict__ bog1,
    const float* __restrict__ gs2, const float* __restrict__ ws2,
    const float* __restrict__ bs2, const float* __restrict__ wsb2,
    const float* __restrict__ wt1, const float* __restrict__ wt2,
    const float* __restrict__ wt3,
    const float* __restrict__ wog2, const float* __restrict__ bog2,
    float* __restrict__ q_o, float* __restrict__ k_o, float* __restrict__ v_o,
    float* __restrict__ g_o, float* __restrict__ og1_o, float* __restrict__ trans_o) {
    // --- LN: one wave per row (waves 8..15 idle through this short phase) ---
    {
        int r = t >> 6;
        if (r < R1) {
            int l = t & 63;
            float s = 0, s2 = 0;
#pragma unroll
            for (int k = 0; k < 2; k++) { float x = sm.lna[r][l + 64 * k]; s += x; s2 += x * x; }
            for (int m = 1; m < 64; m <<= 1) { s += __shfl_xor(s, m); s2 += __shfl_xor(s2, m); }
            float mean = s * (1.0f / 128.0f);
            float rs = rsqrtf(s2 * (1.0f / 128.0f) - mean * mean + 1e-5f);
            float cs = 0, cs2 = 0;
#pragma unroll
            for (int k = 0; k < 2; k++) { float x = sm.cls[r][l + 64 * k]; cs += x; cs2 += x * x; }
            for (int m = 1; m < 64; m <<= 1) { cs += __shfl_xor(cs, m); cs2 += __shfl_xor(cs2, m); }
            float cmean = cs * (1.0f / 128.0f);
            float crs = rsqrtf(cs2 * (1.0f / 128.0f) - cmean * cmean + 1e-5f);
#pragma unroll
            for (int k = 0; k < 2; k++) {
                int c = l + 64 * k;
                sm.lna[r][c] = (sm.lna[r][c] - mean) * rs;
                float cn = (sm.cls[r][c] - cmean) * crs;
                sm.sn1[r][c] = cn * gs1[c];
                sm.sn2[r][c] = cn * gs2[c];
            }
        }
    }
    __syncthreads();

    // --- M1 streams {ws1,wsb1,ws2,wsb2} (t<512) || og1/og2 2-way c-split ---
    if (t < 512) {
        int s = t >> 7, rh = (t >> 6) & 1, col2 = 2 * (t & 63);
        const float* X = (s < 2) ? &sm.sn1[rh * 4][0] : &sm.sn2[rh * 4][0];
        const float* W = (s == 0) ? ws1 : (s == 1) ? wsb1 : (s == 2) ? ws2 : wsb2;
        float2 acc[4] = {{0,0},{0,0},{0,0},{0,0}};
        mv_acc<CC>(X, 0, CC, W, CC, col2, acc);
#pragma unroll
        for (int r = 0; r < 4; r++)
            *(float2*)&sm.tmp[s][rh * 4 + r][col2] = acc[r];
    } else {
        int u = t - 512;
        int s2 = u >> 8, ch = (u >> 7) & 1, rh = (u >> 6) & 1, col2 = 2 * (u & 63);
        const float* W = s2 ? wog2 : wog1;
        float2 acc[4] = {{0,0},{0,0},{0,0},{0,0}};
        mv_acc<CC>(&sm.cls[rh * 4][0], ch * 64, 64, W, CC, col2, acc);
#pragma unroll
        for (int r = 0; r < 4; r++)
            *(float2*)&sm.tmp[4 + s2 * 2 + ch][rh * 4 + r][col2] = acc[r];
    }
    __syncthreads();

    // --- E1: one (row, col) element per thread ---
    float G;
    {
        int rr = t >> 7, o = t & 127;
        float A1 = sm.tmp[0][rr][o], B1 = sm.tmp[1][rr][o];
        float A2 = sm.tmp[2][rr][o], B2 = sm.tmp[3][rr][o];
        float O1 = sm.tmp[4][rr][o] + sm.tmp[5][rr][o];
        float O2 = sm.tmp[6][rr][o] + sm.tmp[7][rr][o];
        float ln = sm.lna[rr][o];
        sm.aln1[rr][o] = sigm(A1 + bs1[o]) * ln + B1;
        sm.a2s [rr][o] = sigm(A2 + bs2[o]) * ln + B2;
        og1_o[(size_t)(n0 + rr) * CC + o] = sigm(O1 + bog1[o]);
        G = sigm(O2 + bog2[o]);
    }
    __syncthreads();

    // --- QKVG streams (t<512, direct global stores) || T12 wt1/wt2 ---
    if (t < 512) {
        int s = t >> 7, rh = (t >> 6) & 1, col2 = 2 * (t & 63);
        const float* W = (s == 0) ? wq : (s == 1) ? wk : (s == 2) ? wv : wg;
        float2 acc[4] = {{0,0},{0,0},{0,0},{0,0}};
        mv_acc<CC>(&sm.aln1[rh * 4][0], 0, CC, W, CC, col2, acc);
        float* dst = (s == 0) ? q_o : (s == 1) ? k_o : (s == 2) ? v_o : g_o;
#pragma unroll
        for (int r = 0; r < 4; r++) {
            float2 v = acc[r];
            if (s == 0) { v.x += bq[col2]; v.y += bq[col2 + 1]; }
            if (s == 3) { v.x = sigm(v.x); v.y = sigm(v.y); }
            *(float2*)&dst[(size_t)(n0 + rh * 4 + r) * CC + col2] = v;
        }
    } else {
        int u = t - 512;
        int sT = u >> 8, rhT = (u >> 7) & 1, colT = 2 * (u & 127);
        const float* W = sT ? wt2 : wt1;
        float2 acc[4] = {{0,0},{0,0},{0,0},{0,0}};
        mv_acc<CC>(&sm.a2s[rhT * 4][0], 0, CC, W, NHID, colT, acc);
        if (sT == 0) {
#pragma unroll
            for (int r = 0; r < 4; r++) {
                float2 h;
                h.x = acc[r].x * sigm(acc[r].x);
                h.y = acc[r].y * sigm(acc[r].y);
                *(float2*)&sm.hid[rhT * 4 + r][colT] = h;
            }
        } else {
            float* w2buf = &sm.tmp[0][0][0];  // 8 KB scratch (tmp consumed in E1)
#pragma unroll
            for (int r = 0; r < 4; r++)
                *(float2*)&w2buf[(rhT * 4 + r) * NHID + colT] = acc[r];
        }
    }
    __syncthreads();
    {   // hid *= wt2-partial: 2048 elements, 2 per thread
        float* hf = &sm.hid[0][0];
        float* w2buf = &sm.tmp[0][0][0];
        hf[t] *= w2buf[t];
        hf[t + 1024] *= w2buf[t + 1024];
    }
    __syncthreads();

    // --- T3: wt3 (256->128), 8-way c-split x 2 row-halves ---
    {
        int g = t >> 6, cq = g & 7, rh = g >> 3, col2 = 2 * (t & 63);
        float2 acc[4] = {{0,0},{0,0},{0,0},{0,0}};
        mv_acc<NHID>(&sm.hid[rh * 4][0], cq * 32, 32, wt3, CC, col2, acc);
#pragma unroll
        for (int r = 0; r < 4; r++)
            *(float2*)&sm.tmp[cq][rh * 4 + r][col2] = acc[r];
    }
    __syncthreads();
    {
        int rr = t >> 7, o = t & 127;
        float s8 = sm.tmp[0][rr][o] + sm.tmp[1][rr][o] + sm.tmp[2][rr][o] + sm.tmp[3][rr][o]
                 + sm.tmp[4][rr][o] + sm.tmp[5][rr][o] + sm.tmp[6][rr][o] + sm.tmp[7][rr][o];
        trans_o[(size_t)(n0 + rr) * CC + o] = G * s8;
    }
}

// ---------------------------------------------------------------------------
// W phase: tmp[cq] = partial of (aln1-scratch rows) @ wo, 8-way c-split.
__device__ __forceinline__ void w_phase(SmemU& sm, int t, const float* __restrict__ wo) {
    int g = t >> 6, cq = g & 7, rh = g >> 3, col2 = 2 * (t & 63);
    float2 acc[4] = {{0,0},{0,0},{0,0},{0,0}};
    mv_acc<CC>(&sm.aln1[rh * 4][0], cq * 16, 16, wo, CC, col2, acc);
#pragma unroll
    for (int r = 0; r < 4; r++)
        *(float2*)&sm.tmp[cq][rh * 4 + r][col2] = acc[r];
}

// ---------------------------------------------------------------------------
// pair-bias body: one (qb,qi,kj) per pid; writes all 3 NB blocks.
__device__ void pb_body(const float* __restrict__ plm, const float* __restrict__ gz,
                        const float* __restrict__ bz, const float* __restrict__ wz,
                        float* __restrict__ pb, int pid) {
    int qb = pid >> 12;
    int qi = (pid >> 7) & 31;
    int kj = pid & 127;
    int n = qb * 32 + qi;
    int kstart = max(0, qb * 32 - 48);
    int m = kstart + kj;
    bool valid = (m < N_ATOM);
    float xn[CZDIM];
    if (valid) {
        const float4* p4 = (const float4*)(plm + ((size_t)n * N_ATOM + m) * CZDIM);
        float x[CZDIM];
#pragma unroll
        for (int i = 0; i < 4; i++) {
            float4 v = p4[i];
            x[4 * i] = v.x; x[4 * i + 1] = v.y; x[4 * i + 2] = v.z; x[4 * i + 3] = v.w;
        }
        float s = 0, s2 = 0;
#pragma unroll
        for (int c = 0; c < CZDIM; c++) { s += x[c]; s2 += x[c] * x[c]; }
        float mean = s * (1.0f / 16.0f);
        float rs = rsqrtf(s2 * (1.0f / 16.0f) - mean * mean + 1e-5f);
#pragma unroll
        for (int c = 0; c < CZDIM; c++) xn[c] = (x[c] - mean) * rs;
    }
#pragma unroll
    for (int b = 0; b < 3; b++) {
        float out[HH] = {0, 0, 0, 0};
        if (valid) {
            const float* gzb = gz + b * CZDIM;
            const float* bzb = bz + b * CZDIM;
            const float* wzb = wz + b * CZDIM * HH;
#pragma unroll
            for (int c = 0; c < CZDIM; c++) {
                float z = xn[c] * gzb[c] + bzb[c];
#pragma unroll
                for (int h = 0; h < HH; h++) out[h] += z * wzb[c * HH + h];
            }
        }
#pragma unroll
        for (int h = 0; h < HH; h++)
            pb[b * PBSTRIDE + (((qb * HH + h) * 32 + qi) << 7) + kj] = out[h];
    }
}

// ---------------------------------------------------------------------------
// Fused first dispatch: blocks [0,256) update block-0; [256,512) pair bias;
// [512,640) amask. 1024 threads.
__global__ __launch_bounds__(1024, 4) void k_first(
    const float* __restrict__ ql, const float* __restrict__ cl,
    const float* __restrict__ plm, const float* __restrict__ gz,
    const float* __restrict__ bz, const float* __restrict__ wz,
    const float* __restrict__ a2t, const float* __restrict__ tm,
    const float* __restrict__ gs1, const float* __restrict__ ws1,
    const float* __restrict__ bs1, const float* __restrict__ wsb1,
    const float* __restrict__ wq, const float* __restrict__ bq,
    const float* __restrict__ wk, const float* __restrict__ wv,
    const float* __restrict__ wg,
    const float* __restrict__ wog1, const float* __restrict__ bog1,
    const float* __restrict__ gs2, const float* __restrict__ ws2,
    const float* __restrict__ bs2, const float* __restrict__ wsb2,
    const float* __restrict__ wt1, const float* __restrict__ wt2,
    const float* __restrict__ wt3,
    const float* __restrict__ wog2, const float* __restrict__ bog2,
    float* __restrict__ q_o, float* __restrict__ k_o, float* __restrict__ v_o,
    float* __restrict__ g_o, float* __restrict__ og1_o, float* __restrict__ trans_o,
    float* __restrict__ pb3, float* __restrict__ amask) {
    __shared__ SmemU sm;
    const int t = threadIdx.x;
    const int bx = blockIdx.x;
    if (bx >= 512) {  // amask: 16 waves, one row each
        int u = bx - 512;
        int wave = t >> 6, lane = t & 63;
        int l = u * 16 + wave;
        float s = 0.0f;
        for (int i = lane; i < NTOK; i += 64) s += a2t[(size_t)l * NTOK + i] * tm[i];
        for (int m = 1; m < 64; m <<= 1) s += __shfl_xor(s, m);
        if (lane == 0) amask[l] = (s - 1.0f) * 1e9f;
        return;
    }
    if (bx >= 256) {  // pair bias
        pb_body(plm, gz, bz, wz, pb3, (bx - 256) * 1024 + t);
        return;
    }
    const int n0 = bx * R1;
    if (t < 256)
        ((float4*)sm.lna)[t] = ((const float4*)(ql + (size_t)n0 * CC))[t];
    else if (t < 512)
        ((float4*)sm.cls)[t - 256] = ((const float4*)(cl + (size_t)n0 * CC))[t - 256];
    __syncthreads();
    adaln_proj_body(sm, t, n0, gs1, ws1, bs1, wsb1, wq, bq, wk, wv, wg, wog1, bog1,
                    gs2, ws2, bs2, wsb2, wt1, wt2, wt3, wog2, bog2,
                    q_o, k_o, v_o, g_o, og1_o, trans_o);
}

// ---------------------------------------------------------------------------
// Later blocks: fused combine (a = og1*((g*o)@wo)+trans) + AdaLN/projections.
__global__ __launch_bounds__(1024, 4) void k_update(
    const float* __restrict__ cl,
    const float* __restrict__ g_in, const float* __restrict__ o_in,
    const float* __restrict__ og1_in, const float* __restrict__ trans_in,
    const float* __restrict__ wo_prev,
    const float* __restrict__ gs1, const float* __restrict__ ws1,
    const float* __restrict__ bs1, const float* __restrict__ wsb1,
    const float* __restrict__ wq, const float* __restrict__ bq,
    const float* __restrict__ wk, const float* __restrict__ wv,
    const float* __restrict__ wg,
    const float* __restrict__ wog1, const float* __restrict__ bog1,
    const float* __restrict__ gs2, const float* __restrict__ ws2,
    const float* __restrict__ bs2, const float* __restrict__ wsb2,
    const float* __restrict__ wt1, const float* __restrict__ wt2,
    const float* __restrict__ wt3,
    const float* __restrict__ wog2, const float* __restrict__ bog2,
    float* __restrict__ q_o, float* __restrict__ k_o, float* __restrict__ v_o,
    float* __restrict__ g_o, float* __restrict__ og1_o, float* __restrict__ trans_o) {
    __shared__ SmemU sm;
    const int t = threadIdx.x;
    const int n0 = blockIdx.x * R1;
    if (t < 256) {
        float4 gv = ((const float4*)(g_in + (size_t)n0 * CC))[t];
        float4 ov = ((const float4*)(o_in + (size_t)n0 * CC))[t];
        float4 p; p.x = gv.x * ov.x; p.y = gv.y * ov.y; p.z = gv.z * ov.z; p.w = gv.w * ov.w;
        ((float4*)sm.aln1)[t] = p;
    } else if (t < 512) {
        ((float4*)sm.cls)[t - 256] = ((const float4*)(cl + (size_t)n0 * CC))[t - 256];
    }
    __syncthreads();
    w_phase(sm, t, wo_prev);
    __syncthreads();
    {   // reduce + gate + residual -> new a in lna
        int rr = t >> 7, o = t & 127;
        float s8 = sm.tmp[0][rr][o] + sm.tmp[1][rr][o] + sm.tmp[2][rr][o] + sm.tmp[3][rr][o]
                 + sm.tmp[4][rr][o] + sm.tmp[5][rr][o] + sm.tmp[6][rr][o] + sm.tmp[7][rr][o];
        sm.lna[rr][o] = og1_in[(size_t)(n0 + rr) * CC + o] * s8
                      + trans_in[(size_t)(n0 + rr) * CC + o];
    }
    __syncthreads();
    adaln_proj_body(sm, t, n0, gs1, ws1, bs1, wsb1, wq, bq, wk, wv, wg, wog1, bog1,
                    gs2, ws2, bs2, wsb2, wt1, wt2, wt3, wog2, bog2,
                    q_o, k_o, v_o, g_o, og1_o, trans_o);
}

// ---------------------------------------------------------------------------
// Final combine only (writes d_out): a_new = og1 * ((g*o) @ wo) + trans
__global__ __launch_bounds__(1024, 4) void k_combine(const float* __restrict__ g,
                                                     const float* __restrict__ o_in,
                                                     const float* __restrict__ og1,
                                                     const float* __restrict__ trans,
                                                     const float* __restrict__ wo,
                                                     float* __restrict__ a_out) {
    __shared__ SmemU sm;
    const int t = threadIdx.x;
    const int n0 = blockIdx.x * R1;
    if (t < 256) {
        float4 gv = ((const float4*)(g + (size_t)n0 * CC))[t];
        float4 ov = ((const float4*)(o_in + (size_t)n0 * CC))[t];
        float4 p; p.x = gv.x * ov.x; p.y = gv.y * ov.y; p.z = gv.z * ov.z; p.w = gv.w * ov.w;
        ((float4*)sm.aln1)[t] = p;
    }
    __syncthreads();
    w_phase(sm, t, wo);
    __syncthreads();
    {
        int rr = t >> 7, o = t & 127;
        float s8 = sm.tmp[0][rr][o] + sm.tmp[1][rr][o] + sm.tmp[2][rr][o] + sm.tmp[3][rr][o]
                 + sm.tmp[4][rr][o] + sm.tmp[5][rr][o] + sm.tmp[6][rr][o] + sm.tmp[7][rr][o];
        a_out[(size_t)(n0 + rr) * CC + o] =
            og1[(size_t)(n0 + rr) * CC + o] * s8
            + trans[(size_t)(n0 + rr) * CC + o];
    }
}

// ---------------------------------------------------------------------------
// K_attn: one wg per (query block, head). 1024 threads, 32 per query row.
__global__ __launch_bounds__(1024, 4) void k_attn(const float* __restrict__ q,
                                                  const float* __restrict__ k,
                                                  const float* __restrict__ v,
                                                  const float* __restrict__ pb,
                                                  const float* __restrict__ amask,
                                                  float* __restrict__ o_out) {
    __shared__ __align__(16) float qs[32][36];
    __shared__ __align__(16) float ks[128][36];
    __shared__ __align__(16) float vs[128][36];
    __shared__ __align__(16) float ps[32][132];
    const int t = threadIdx.x;
    const int qb = blockIdx.x >> 2, h = blockIdx.x & 3;
    const int n0 = qb * 32;
    const int kstart = max(0, qb * 32 - 48);
    const int nk = min(N_ATOM, qb * 32 + 80) - kstart;

    if (t < 256) {  // stage q: 32 rows x 8 float4
        int qi = t >> 3, dq = t & 7;
        *(float4*)&qs[qi][dq * 4] = *(const float4*)&q[(n0 + qi) * CC + h * CHD + dq * 4];
    }
    {   // stage k,v: each thread one float4 of each
        int kj = t >> 3, dq = t & 7;
        int m = kstart + kj;
        float4 kv = {0, 0, 0, 0}, vv = {0, 0, 0, 0};
        if (m < N_ATOM) {
            kv = *(const float4*)&k[m * CC + h * CHD + dq * 4];
            vv = *(const float4*)&v[m * CC + h * CHD + dq * 4];
        }
        *(float4*)&ks[kj][dq * 4] = kv;
        *(float4*)&vs[kj][dq * 4] = vv;
    }
    __syncthreads();

    const int qi = t >> 5, j32 = t & 31;  // 32 threads per query row (half-wave)
    float4 qr[8];
#pragma unroll
    for (int dq = 0; dq < 8; dq++) qr[dq] = *(const float4*)&qs[qi][dq * 4];

    const float isc = 0.17677669529663687f;  // 1/sqrt(32)
    const float* pbrow = pb + ((qb * HH + h) * 32 + qi) * 128;
    float lr[4];
    float mx = -1e30f;
#pragma unroll
    for (int jj = 0; jj < 4; jj++) {
        int kj = j32 + 32 * jj;
        float acc = 0;
#pragma unroll
        for (int dq = 0; dq < 8; dq++) {
            float4 kk = *(const float4*)&ks[kj][dq * 4];
            acc += qr[dq].x * kk.x + qr[dq].y * kk.y + qr[dq].z * kk.z + qr[dq].w * kk.w;
        }
        float l = (kj < nk) ? (acc * isc + pbrow[kj] + amask[kstart + kj]) : -1e9f;
        lr[jj] = l;
        mx = fmaxf(mx, l);
    }
    for (int m = 1; m < 32; m <<= 1) mx = fmaxf(mx, __shfl_xor(mx, m));
    float sum = 0;
#pragma unroll
    for (int jj = 0; jj < 4; jj++) { lr[jj] = __expf(lr[jj] - mx); sum += lr[jj]; }
    for (int m = 1; m < 32; m <<= 1) sum += __shfl_xor(sum, m);
    float rd = 1.0f / sum;
#pragma unroll
    for (int jj = 0; jj < 4; jj++) ps[qi][j32 + 32 * jj] = lr[jj] * rd;
    __syncthreads();

    if (t < 512) {  // PV: 16 threads per row, float2 over 32 dims
        const int qi2 = t >> 4, d0 = (t & 15) * 2;
        float2 acc = {0, 0};
        for (int kj = 0; kj < 128; kj += 4) {
            float4 pv = *(const float4*)&ps[qi2][kj];
            float2 v0 = *(const float2*)&vs[kj][d0];
            float2 v1 = *(const float2*)&vs[kj + 1][d0];
            float2 v2 = *(const float2*)&vs[kj + 2][d0];
            float2 v3 = *(const float2*)&vs[kj + 3][d0];
            acc.x += pv.x * v0.x + pv.y * v1.x + pv.z * v2.x + pv.w * v3.x;
            acc.y += pv.x * v0.y + pv.y * v1.y + pv.z * v2.y + pv.w * v3.y;
        }
        *(float2*)&o_out[(n0 + qi2) * CC + h * CHD + d0] = acc;
    }
}

// ---------------------------------------------------------------------------
extern "C" void kernel_launch(void* const* d_in, const int* in_sizes, int n_in,
                              void* d_out, int out_size, void* d_ws, size_t ws_size,
                              hipStream_t stream) {
    const float* ql   = (const float*)d_in[0];
    const float* cl   = (const float*)d_in[1];
    const float* plm  = (const float*)d_in[2];
    const float* a2t  = (const float*)d_in[3];
    const float* tm   = (const float*)d_in[4];
    const float* ada1_gs  = (const float*)d_in[5];
    const float* ada1_ws  = (const float*)d_in[6];
    const float* ada1_bs  = (const float*)d_in[7];
    const float* ada1_wsb = (const float*)d_in[8];
    const float* wq  = (const float*)d_in[9];
    const float* bq  = (const float*)d_in[10];
    const float* wk  = (const float*)d_in[11];
    const float* wv  = (const float*)d_in[12];
    const float* gz  = (const float*)d_in[13];
    const float* bz  = (const float*)d_in[14];
    const float* wz  = (const float*)d_in[15];
    const float* wg  = (const float*)d_in[16];
    const float* wo  = (const float*)d_in[17];
    const float* wog1 = (const float*)d_in[18];
    const float* bog1 = (const float*)d_in[19];
    const float* ada2_gs  = (const float*)d_in[20];
    const float* ada2_ws  = (const float*)d_in[21];
    const float* ada2_bs  = (const float*)d_in[22];
    const float* ada2_wsb = (const float*)d_in[23];
    const float* wt1 = (const float*)d_in[24];
    const float* wt2 = (const float*)d_in[25];
    const float* wt3 = (const float*)d_in[26];
    const float* wog2 = (const float*)d_in[27];
    const float* bog2 = (const float*)d_in[28];

    const size_t NC = (size_t)N_ATOM * CC;  // 262144
    float* ws = (float*)d_ws;
    float* q_    = ws + 0 * NC;
    float* k_    = ws + 1 * NC;
    float* v_    = ws + 2 * NC;
    float* g_    = ws + 3 * NC;
    float* og1_  = ws + 4 * NC;
    float* tr_   = ws + 5 * NC;
    float* o_    = ws + 6 * NC;
    float* pb3   = ws + 7 * NC;                      // 3 * 1048576 floats
    float* am    = ws + 7 * NC + 3 * PBSTRIDE;       // 2048 floats

    k_first<<<640, 1024, 0, stream>>>(
        ql, cl, plm, gz, bz, wz, a2t, tm,
        ada1_gs, ada1_ws, ada1_bs, ada1_wsb,
        wq, bq, wk, wv, wg, wog1, bog1,
        ada2_gs, ada2_ws, ada2_bs, ada2_wsb,
        wt1, wt2, wt3, wog2, bog2,
        q_, k_, v_, g_, og1_, tr_, pb3, am);

    for (int b = 0; b < 3; b++) {
        if (b > 0) {
            k_update<<<N_ATOM / R1, 1024, 0, stream>>>(
                cl, g_, o_, og1_, tr_, wo + (size_t)(b - 1) * CC * CC,
                ada1_gs + b * CC, ada1_ws + (size_t)b * CC * CC, ada1_bs + b * CC,
                ada1_wsb + (size_t)b * CC * CC,
                wq + (size_t)b * CC * CC, bq + b * CC, wk + (size_t)b * CC * CC,
                wv + (size_t)b * CC * CC, wg + (size_t)b * CC * CC,
                wog1 + (size_t)b * CC * CC, bog1 + b * CC,
                ada2_gs + b * CC, ada2_ws + (size_t)b * CC * CC, ada2_bs + b * CC,
                ada2_wsb + (size_t)b * CC * CC,
                wt1 + (size_t)b * CC * NHID, wt2 + (size_t)b * CC * NHID,
                wt3 + (size_t)b * NHID * CC,
                wog2 + (size_t)b * CC * CC, bog2 + b * CC,
                q_, k_, v_, g_, og1_, tr_);
        }
        k_attn<<<NQB * HH, 1024, 0, stream>>>(q_, k_, v_, pb3 + (size_t)b * PBSTRIDE, am, o_);
    }
    k_combine<<<N_ATOM / R1, 1024, 0, stream>>>(g_, o_, og1_, tr_, wo + (size_t)2 * CC * CC,
                                                (float*)d_out);
}